// Round 7
// baseline (176.692 us; speedup 1.0000x reference)
//
#include <hip/hip_runtime.h>
#include <hip/hip_bf16.h>

#define B_N 16
#define S_LEN 2048
#define D_DIM 128
#define TK 32
#define NT (S_LEN / TK)   // 64 tiles, each wave streams all of them

typedef __attribute__((ext_vector_type(16))) float f32x16;
typedef __attribute__((ext_vector_type(8)))  short short8;
typedef const __attribute__((address_space(1))) void* gp1;
typedef __attribute__((address_space(3))) void* sp3;
#define GLL(g, l) __builtin_amdgcn_global_load_lds((gp1)(const void*)(g), (sp3)(void*)(l), 16, 0, 0)

// s_waitcnt SIMM16: vmcnt[3:0]=b3:0, expcnt=b6:4, lgkmcnt=b11:8, vmcnt[5:4]=b15:14
#define WAITCNT_VM16 0x4F70   // vmcnt<=16, lgkm/exp unconstrained
#define WAITCNT_VM0  0x0F70   // vmcnt==0,  lgkm/exp unconstrained

static __device__ __forceinline__ unsigned short f2bf(float f) {
  unsigned u = __builtin_bit_cast(unsigned, f);
  return (unsigned short)((u + 0x7fffu + ((u >> 16) & 1u)) >> 16);  // RNE
}

static __device__ __forceinline__ unsigned pk_bf16(float a, float b) {
#if __has_builtin(__builtin_amdgcn_cvt_pk_bf16_f32)
  typedef __attribute__((ext_vector_type(2))) __bf16 bf16x2;
  bf16x2 r = __builtin_amdgcn_cvt_pk_bf16_f32(a, b);
  return __builtin_bit_cast(unsigned, r);
#else
  return (unsigned)f2bf(a) | ((unsigned)f2bf(b) << 16);
#endif
}

// ---------------- prepass: K -> bf16 row-major; V -> bf16 transposed [b][d][s] ----------------
__global__ __launch_bounds__(256)
void prep_kernel(const float* __restrict__ K, const float* __restrict__ V,
                 unsigned short* __restrict__ Kb, unsigned short* __restrict__ VT) {
  __shared__ unsigned short lds[64 * 66];
  int bx = blockIdx.x;
  int t  = threadIdx.x;
  if (bx < 4096) {
    size_t i = ((size_t)bx * 256 + t) * 4;
    float4 v = *(const float4*)(K + i);
    *(uint2*)(Kb + i) = make_uint2(pk_bf16(v.x, v.y), pk_bf16(v.z, v.w));
  } else {
    int bi = bx - 4096;                 // 1024 = 16 b x 32 st x 2 dt
    int b  = bi & 15;
    int st = (bi >> 4) & 31;
    int dt = bi >> 9;
    const float* Vb = V + ((size_t)b * S_LEN + st * 64) * D_DIM + dt * 64;
    unsigned short* VTb = VT + ((size_t)b * D_DIM + dt * 64) * S_LEN + st * 64;
#pragma unroll
    for (int rep = 0; rep < 4; ++rep) {
      int idx = rep * 256 + t;
      int i  = idx >> 4;                // s-local 0..63
      int j4 = (idx & 15) * 4;          // d-local
      float4 v = *(const float4*)(Vb + (size_t)i * D_DIM + j4);
      *(uint2*)&lds[i * 66 + j4] = make_uint2(pk_bf16(v.x, v.y), pk_bf16(v.z, v.w));
    }
    __syncthreads();
#pragma unroll
    for (int rep = 0; rep < 4; ++rep) {
      int idx = rep * 256 + t;
      int dd = idx >> 4;                // d-local 0..63
      int s4 = (idx & 15) * 4;          // s-local
      unsigned short e0 = lds[(s4 + 0) * 66 + dd];
      unsigned short e1 = lds[(s4 + 1) * 66 + dd];
      unsigned short e2 = lds[(s4 + 2) * 66 + dd];
      unsigned short e3 = lds[(s4 + 3) * 66 + dd];
      *(uint2*)(VTb + (size_t)dd * S_LEN + s4) =
          make_uint2((unsigned)e0 | ((unsigned)e1 << 16),
                     (unsigned)e2 | ((unsigned)e3 << 16));
    }
  }
}

// -------- main kernel: 4 waves/block, wave-private tiles, NO barriers in loop --------
__global__ __launch_bounds__(256, 1)
void attn_kernel(const float* __restrict__ Q, const unsigned short* __restrict__ Kb,
                 const unsigned short* __restrict__ VT, float* __restrict__ O) {
  // per wave: 32 KB private = kbuf 2x8KB + vbuf 2x8KB
  __shared__ __align__(16) char smem[131072];

  const int tid  = threadIdx.x;
  const int wave = tid >> 6;
  const int lane = tid & 63;
  const int l32  = lane & 31;
  const int half = lane >> 5;

  const int i     = blockIdx.x;
  const int b     = (i & 7) * 2 + ((i >> 3) & 1);   // XCD swizzle: batch pair per XCD
  const int qtile = i >> 4;
  const int qbase = qtile * 128 + wave * 32;        // this wave's 32 q-rows

  const float* Qb = Q + (size_t)b * S_LEN * D_DIM;
  const unsigned short* Kbb = Kb + (size_t)b * S_LEN * D_DIM;
  const unsigned short* VTb = VT + (size_t)b * D_DIM * S_LEN;

  char* kbase = smem + wave * 32768;          // 2 bufs x 8192 B
  char* vbase = kbase + 16384;                // 2 bufs x 8192 B

  // ---- per-chunk global element offsets (lane-dependent, hoisted) ----
  unsigned kGo[8], vGo[8];
#pragma unroll
  for (int c = 0; c < 8; ++c) {
    int rl  = 4 * c + (lane >> 4);
    int lbk = (lane & 15) ^ (rl & 15);
    kGo[c] = (unsigned)(rl * D_DIM + lbk * 8);
    int dv  = 16 * c + (lane >> 2);
    int lbv = (lane & 3) ^ ((dv >> 1) & 3);
    vGo[c] = (unsigned)(dv * S_LEN + lbv * 8);
  }

  // ---- tile 0 DMA (16 GLL) ----
#pragma unroll
  for (int c = 0; c < 8; ++c) {
    GLL(Kbb + kGo[c], kbase + c * 1024);
    GLL(VTb + vGo[c], vbase + c * 1024);
  }

  // ---- LDS read byte-offsets (verified swizzle) ----
  int kOff[8], vOff[8];
#pragma unroll
  for (int ks = 0; ks < 8; ++ks)
    kOff[ks] = (l32 * D_DIM + (((ks << 1) + half) ^ (l32 & 15)) * 8) * 2;
#pragma unroll
  for (int ks2 = 0; ks2 < 2; ++ks2)
#pragma unroll
    for (int dt = 0; dt < 4; ++dt) {
      int dv = dt * 32 + l32;
      int pv = ((ks2 << 1) + half) ^ ((dv >> 1) & 3);
      vOff[ks2 * 4 + dt] = (dv * TK + pv * 8) * 2;
    }

  // ---- Q fragments, pre-scaled by 1/sqrt(d)*log2(e) ----
  const float SC = 0.08838834764831845f * 1.4426950408889634f;
  short8 qa[8];
  {
    const float* qp = Qb + (size_t)(qbase + l32) * D_DIM + half * 8;
#pragma unroll
    for (int ks = 0; ks < 8; ++ks) {
      float4 a0 = *(const float4*)(qp + ks * 16);
      float4 a1 = *(const float4*)(qp + ks * 16 + 4);
      union { unsigned u[4]; short8 s; } pu;
      pu.u[0] = pk_bf16(a0.x * SC, a0.y * SC);
      pu.u[1] = pk_bf16(a0.z * SC, a0.w * SC);
      pu.u[2] = pk_bf16(a1.x * SC, a1.y * SC);
      pu.u[3] = pk_bf16(a1.z * SC, a1.w * SC);
      qa[ks] = pu.s;
    }
  }

  const f32x16 zf16 = {0.f,0.f,0.f,0.f,0.f,0.f,0.f,0.f,0.f,0.f,0.f,0.f,0.f,0.f,0.f,0.f};
  f32x16 oacc[4];
#pragma unroll
  for (int dt = 0; dt < 4; ++dt) oacc[dt] = zf16;
  float lp[4] = {0.f, 0.f, 0.f, 0.f};

  for (int t = 0; t < NT; ++t) {
    const int cb = t & 1;
    const char* kbc = kbase + cb * 8192;
    const char* vbc = vbase + cb * 8192;

    if (t + 1 < NT) {
      // issue DMA(t+1) into the other buffer (wave-private, no cross-wave hazard),
      // then wait only for the 16 OLDEST vm ops = DMA(t). Free-running pipeline.
      const int nb = cb ^ 1;
      const unsigned short* kt = Kbb + (size_t)(t + 1) * TK * D_DIM;
      const unsigned short* vt = VTb + (size_t)(t + 1) * TK;
#pragma unroll
      for (int c = 0; c < 8; ++c) {
        GLL(kt + kGo[c], kbase + nb * 8192 + c * 1024);
        GLL(vt + vGo[c], vbase + nb * 8192 + c * 1024);
      }
      __builtin_amdgcn_s_waitcnt(WAITCNT_VM16);
    } else {
      __builtin_amdgcn_s_waitcnt(WAITCNT_VM0);
    }

    // ---- S^T = K Q^T (regs = keys, cols = q) ----
    f32x16 sacc = zf16;
#pragma unroll
    for (int ks = 0; ks < 8; ++ks) {
      short8 kf = *(const short8*)(kbc + kOff[ks]);
      sacc = __builtin_amdgcn_mfma_f32_32x32x16_bf16(kf, qa[ks], sacc, 0, 0, 0);
    }

    // ---- max-free softmax (scale folded into Q) ----
    float p[16];
#pragma unroll
    for (int r = 0; r < 16; ++r) p[r] = exp2f(sacc[r]);
#pragma unroll
    for (int r = 0; r < 16; ++r) lp[r & 3] += p[r];
    unsigned w[8];
#pragma unroll
    for (int j = 0; j < 8; ++j) w[j] = pk_bf16(p[2 * j], p[2 * j + 1]);

    // ---- P^T -> A-layout via half-swap + O += P V ----
#pragma unroll
    for (int ks2 = 0; ks2 < 2; ++ks2) {
      const int a = ks2 * 4;
      unsigned x0 = (unsigned)__shfl_xor((int)w[a + 0], 32);
      unsigned x1 = (unsigned)__shfl_xor((int)w[a + 1], 32);
      unsigned x2 = (unsigned)__shfl_xor((int)w[a + 2], 32);
      unsigned x3 = (unsigned)__shfl_xor((int)w[a + 3], 32);
      union { unsigned u[4]; short8 s; } pu;
      pu.u[0] = half ? x2 : w[a + 0];
      pu.u[1] = half ? x3 : w[a + 1];
      pu.u[2] = half ? w[a + 2] : x0;
      pu.u[3] = half ? w[a + 3] : x1;
      short8 pf = pu.s;
#pragma unroll
      for (int dt = 0; dt < 4; ++dt) {
        short8 vf = *(const short8*)(vbc + vOff[ks2 * 4 + dt]);
        oacc[dt] = __builtin_amdgcn_mfma_f32_32x32x16_bf16(pf, vf, oacc[dt], 0, 0, 0);
      }
    }
  }

  // ---- row sums (full 2048 keys seen by this wave) ----
  float lt = (lp[0] + lp[1]) + (lp[2] + lp[3]);
  lt += __shfl_xor(lt, 32);   // lt = row sum for q = l32 (both halves)

  // ---- epilogue: normalize + store (no merge needed) ----
  float* Ob = O + (size_t)b * S_LEN * D_DIM;
#pragma unroll
  for (int reg = 0; reg < 16; ++reg) {
    int row = (reg & 3) + 8 * (reg >> 2) + 4 * half;
    float linv = 1.f / __shfl(lt, row);   // broadcast row-sum of q-row `row`
#pragma unroll
    for (int dt = 0; dt < 4; ++dt)
      Ob[(size_t)(qbase + row) * D_DIM + dt * 32 + l32] = oacc[dt][reg] * linv;
  }
}

extern "C" void kernel_launch(void* const* d_in, const int* in_sizes, int n_in,
                              void* d_out, int out_size, void* d_ws, size_t ws_size,
                              hipStream_t stream) {
  const float* Q = (const float*)d_in[0];
  const float* K = (const float*)d_in[1];
  const float* V = (const float*)d_in[2];
  float* O = (float*)d_out;
  unsigned short* Kb = (unsigned short*)d_ws;                       // 8.4 MB
  unsigned short* VT = Kb + (size_t)B_N * S_LEN * D_DIM;            // 8.4 MB
  prep_kernel<<<dim3(4096 + 1024), dim3(256), 0, stream>>>(K, V, Kb, VT);
  attn_kernel<<<dim3(256), dim3(256), 0, stream>>>(Q, Kb, VT, O);
}

// Round 9
// 170.254 us; speedup vs baseline: 1.0378x; 1.0378x over previous
//
#include <hip/hip_runtime.h>
#include <hip/hip_bf16.h>

#define B_N 16
#define S_LEN 2048
#define D_DIM 128
#define TK 32
#define NKI 16            // iters per key-group (4 kg x 16 x 32 = 2048 keys)

typedef __attribute__((ext_vector_type(16))) float f32x16;
typedef __attribute__((ext_vector_type(8)))  short short8;
typedef const __attribute__((address_space(1))) void* gp1;
typedef __attribute__((address_space(3))) void* sp3;
#define GLL(g, l) __builtin_amdgcn_global_load_lds((gp1)(const void*)(g), (sp3)(void*)(l), 16, 0, 0)

static __device__ __forceinline__ unsigned short f2bf(float f) {
  unsigned u = __builtin_bit_cast(unsigned, f);
  return (unsigned short)((u + 0x7fffu + ((u >> 16) & 1u)) >> 16);  // RNE
}

static __device__ __forceinline__ unsigned pk_bf16(float a, float b) {
#if __has_builtin(__builtin_amdgcn_cvt_pk_bf16_f32)
  typedef __attribute__((ext_vector_type(2))) __bf16 bf16x2;
  bf16x2 r = __builtin_amdgcn_cvt_pk_bf16_f32(a, b);
  return __builtin_bit_cast(unsigned, r);
#else
  return (unsigned)f2bf(a) | ((unsigned)f2bf(b) << 16);
#endif
}

// ---------------- prepass: K -> bf16 row-major; V -> bf16 transposed [b][d][s] ----------------
__global__ __launch_bounds__(256)
void prep_kernel(const float* __restrict__ K, const float* __restrict__ V,
                 unsigned short* __restrict__ Kb, unsigned short* __restrict__ VT) {
  __shared__ unsigned short lds[64 * 66];
  int bx = blockIdx.x;
  int t  = threadIdx.x;
  if (bx < 4096) {
    size_t i = ((size_t)bx * 256 + t) * 4;
    float4 v = *(const float4*)(K + i);
    *(uint2*)(Kb + i) = make_uint2(pk_bf16(v.x, v.y), pk_bf16(v.z, v.w));
  } else {
    int bi = bx - 4096;                 // 1024 = 16 b x 32 st x 2 dt
    int b  = bi & 15;
    int st = (bi >> 4) & 31;
    int dt = bi >> 9;
    const float* Vb = V + ((size_t)b * S_LEN + st * 64) * D_DIM + dt * 64;
    unsigned short* VTb = VT + ((size_t)b * D_DIM + dt * 64) * S_LEN + st * 64;
#pragma unroll
    for (int rep = 0; rep < 4; ++rep) {
      int idx = rep * 256 + t;
      int i  = idx >> 4;
      int j4 = (idx & 15) * 4;
      float4 v = *(const float4*)(Vb + (size_t)i * D_DIM + j4);
      *(uint2*)&lds[i * 66 + j4] = make_uint2(pk_bf16(v.x, v.y), pk_bf16(v.z, v.w));
    }
    __syncthreads();
#pragma unroll
    for (int rep = 0; rep < 4; ++rep) {
      int idx = rep * 256 + t;
      int dd = idx >> 4;
      int s4 = (idx & 15) * 4;
      unsigned short e0 = lds[(s4 + 0) * 66 + dd];
      unsigned short e1 = lds[(s4 + 1) * 66 + dd];
      unsigned short e2 = lds[(s4 + 2) * 66 + dd];
      unsigned short e3 = lds[(s4 + 3) * 66 + dd];
      *(uint2*)(VTb + (size_t)dd * S_LEN + s4) =
          make_uint2((unsigned)e0 | ((unsigned)e1 << 16),
                     (unsigned)e2 | ((unsigned)e3 << 16));
    }
  }
}

// ---- main: 512 thr = 2 q-groups(64 rows, 2 A-sets) x 4 key-groups(512 keys) ----
__global__ __launch_bounds__(512, 2)
void attn_kernel(const float* __restrict__ Q, const unsigned short* __restrict__ Kb,
                 const unsigned short* __restrict__ VT, float* __restrict__ O) {
  // tiles: kg block at kg*32768: K[2][8192B] then V[2][8192B]
  // merge overlay (post-loop): 4 slots x 32KB at 0; larr at 131072 (2KB)
  __shared__ __align__(16) char smem[133120];

  const int tid  = threadIdx.x;
  const int wave = tid >> 6;
  const int qg   = wave & 1;            // q-group: 64 rows
  const int kg   = wave >> 1;           // key-group: 512 keys
  const int lane = tid & 63;
  const int l32  = lane & 31;
  const int half = lane >> 5;

  const int i     = blockIdx.x;
  const int b     = (i & 7) * 2 + ((i >> 3) & 1);   // XCD swizzle
  const int qtile = i >> 4;
  const int qbase = qtile * 128 + qg * 64;          // this wave's 64 q-rows
  const int KB0   = kg * 512;                       // first key of this group

  const float* Qb = Q + (size_t)b * S_LEN * D_DIM;
  const unsigned short* Kbb = Kb + (size_t)b * S_LEN * D_DIM;
  const unsigned short* VTb = VT + (size_t)b * D_DIM * S_LEN;

  char* kbase = smem + kg * 32768;
  char* vbase = kbase + 16384;

  // ---- DMA chunk offsets: wave qg=0 stages K (8 GLL), qg=1 stages V (8 GLL) ----
  unsigned go[8];
#pragma unroll
  for (int c = 0; c < 8; ++c) {
    if (qg == 0) {
      int rl  = 4 * c + (lane >> 4);
      int lbk = (lane & 15) ^ (rl & 15);
      go[c] = (unsigned)(rl * D_DIM + lbk * 8);
    } else {
      int dv  = 16 * c + (lane >> 2);
      int lbv = (lane & 3) ^ ((dv >> 1) & 3);
      go[c] = (unsigned)(dv * S_LEN + lbv * 8);
    }
  }
  const unsigned short* gsrc0 = (qg == 0) ? Kbb + (size_t)KB0 * D_DIM : VTb + KB0;
  const unsigned gstep = (qg == 0) ? TK * D_DIM : TK;   // per-tile advance (elements)
  char* ldst = (qg == 0) ? kbase : vbase;

  // tile 0 DMA
#pragma unroll
  for (int c = 0; c < 8; ++c) GLL(gsrc0 + go[c], ldst + c * 1024);

  // ---- LDS read byte-offsets (verified swizzle) ----
  int kOff[8], vOff[8];
#pragma unroll
  for (int ks = 0; ks < 8; ++ks)
    kOff[ks] = (l32 * D_DIM + (((ks << 1) + half) ^ (l32 & 15)) * 8) * 2;
#pragma unroll
  for (int ks2 = 0; ks2 < 2; ++ks2)
#pragma unroll
    for (int dt = 0; dt < 4; ++dt) {
      int dv = dt * 32 + l32;
      int pv = ((ks2 << 1) + half) ^ ((dv >> 1) & 3);
      vOff[ks2 * 4 + dt] = (dv * TK + pv * 8) * 2;
    }

  // ---- Q fragments: 2 A-sets, pre-scaled by 1/sqrt(d)*log2(e) ----
  const float SC = 0.08838834764831845f * 1.4426950408889634f;
  short8 qa[2][8];
#pragma unroll
  for (int s = 0; s < 2; ++s) {
    const float* qp = Qb + (size_t)(qbase + s * 32 + l32) * D_DIM + half * 8;
#pragma unroll
    for (int ks = 0; ks < 8; ++ks) {
      float4 a0 = *(const float4*)(qp + ks * 16);
      float4 a1 = *(const float4*)(qp + ks * 16 + 4);
      union { unsigned u[4]; short8 s8; } pu;
      pu.u[0] = pk_bf16(a0.x * SC, a0.y * SC);
      pu.u[1] = pk_bf16(a0.z * SC, a0.w * SC);
      pu.u[2] = pk_bf16(a1.x * SC, a1.y * SC);
      pu.u[3] = pk_bf16(a1.z * SC, a1.w * SC);
      qa[s][ks] = pu.s8;
    }
  }

  const f32x16 zf16 = {0.f,0.f,0.f,0.f,0.f,0.f,0.f,0.f,0.f,0.f,0.f,0.f,0.f,0.f,0.f,0.f};
  f32x16 oacc[2][4];
#pragma unroll
  for (int s = 0; s < 2; ++s)
#pragma unroll
    for (int dt = 0; dt < 4; ++dt) oacc[s][dt] = zf16;
  float lp0 = 0.f, lp1 = 0.f;

  for (int t = 0; t < NKI; ++t) {
    __syncthreads();  // drains DMA(t); all waves done with buf (t+1)&1
    const int cb = t & 1;
    const char* kbc = kbase + cb * 8192;
    const char* vbc = vbase + cb * 8192;

    if (t + 1 < NKI) {  // DMA(t+1) flies during compute(t)
      const unsigned short* gs = gsrc0 + (size_t)(t + 1) * gstep;
      char* ld = ldst + ((t + 1) & 1) * 8192;
#pragma unroll
      for (int c = 0; c < 8; ++c) GLL(gs + go[c], ld + c * 1024);
    }

    // ---- S^T = K Q^T : shared kf feeds both A-sets (2 independent chains) ----
    f32x16 sa0 = zf16, sa1 = zf16;
#pragma unroll
    for (int ks = 0; ks < 8; ++ks) {
      short8 kf = *(const short8*)(kbc + kOff[ks]);
      sa0 = __builtin_amdgcn_mfma_f32_32x32x16_bf16(kf, qa[0][ks], sa0, 0, 0, 0);
      sa1 = __builtin_amdgcn_mfma_f32_32x32x16_bf16(kf, qa[1][ks], sa1, 0, 0, 0);
    }

    // ---- max-free softmax for both sets ----
    float p0[16], p1[16];
#pragma unroll
    for (int r = 0; r < 16; ++r) { p0[r] = exp2f(sa0[r]); p1[r] = exp2f(sa1[r]); }
#pragma unroll
    for (int r = 0; r < 16; ++r) { lp0 += p0[r]; lp1 += p1[r]; }
    unsigned w0[8], w1[8];
#pragma unroll
    for (int j = 0; j < 8; ++j) {
      w0[j] = pk_bf16(p0[2 * j], p0[2 * j + 1]);
      w1[j] = pk_bf16(p1[2 * j], p1[2 * j + 1]);
    }

    // ---- P^T -> A-layout via half-swap (shuffles UNCONDITIONAL, select diverges) ----
#pragma unroll
    for (int ks2 = 0; ks2 < 2; ++ks2) {
      const int a = ks2 * 4;
      unsigned x00 = (unsigned)__shfl_xor((int)w0[a + 0], 32);
      unsigned x01 = (unsigned)__shfl_xor((int)w0[a + 1], 32);
      unsigned x02 = (unsigned)__shfl_xor((int)w0[a + 2], 32);
      unsigned x03 = (unsigned)__shfl_xor((int)w0[a + 3], 32);
      unsigned x10 = (unsigned)__shfl_xor((int)w1[a + 0], 32);
      unsigned x11 = (unsigned)__shfl_xor((int)w1[a + 1], 32);
      unsigned x12 = (unsigned)__shfl_xor((int)w1[a + 2], 32);
      unsigned x13 = (unsigned)__shfl_xor((int)w1[a + 3], 32);
      union { unsigned u[4]; short8 s8; } q0, q1;
      q0.u[0] = half ? x02 : w0[a + 0];
      q0.u[1] = half ? x03 : w0[a + 1];
      q0.u[2] = half ? w0[a + 2] : x00;
      q0.u[3] = half ? w0[a + 3] : x01;
      q1.u[0] = half ? x12 : w1[a + 0];
      q1.u[1] = half ? x13 : w1[a + 1];
      q1.u[2] = half ? w1[a + 2] : x10;
      q1.u[3] = half ? w1[a + 3] : x11;
      short8 pf0 = q0.s8, pf1 = q1.s8;
#pragma unroll
      for (int dt = 0; dt < 4; ++dt) {
        short8 vf = *(const short8*)(vbc + vOff[ks2 * 4 + dt]);
        oacc[0][dt] = __builtin_amdgcn_mfma_f32_32x32x16_bf16(pf0, vf, oacc[0][dt], 0, 0, 0);
        oacc[1][dt] = __builtin_amdgcn_mfma_f32_32x32x16_bf16(pf1, vf, oacc[1][dt], 0, 0, 0);
      }
    }
  }

  // ---- per-set row sums (column q = l32) over this key-group ----
  float lt0 = lp0 + __shfl_xor(lp0, 32);
  float lt1 = lp1 + __shfl_xor(lp1, 32);

  // ---- 4-way split-K merge: tree in LDS (overlaying dead tile space) ----
  __syncthreads();
  float* slot = (float*)smem;                    // 4 slots x 8192 floats
  float* larr = (float*)(smem + 131072);         // [kg-1][qg][set][32]
  if (kg != 0 && half == 0) {
    float* lw = larr + ((kg - 1) * 2 + qg) * 64;
    lw[l32]      = lt0;
    lw[32 + l32] = lt1;
  }
  // round 1: kg1 -> slot[qg*2+0], kg3 -> slot[qg*2+1]
  if (kg == 1 || kg == 3) {
    float* os = slot + (qg * 2 + (kg >> 1)) * 8192;
#pragma unroll
    for (int s = 0; s < 2; ++s)
#pragma unroll
      for (int reg = 0; reg < 16; ++reg) {
        int row = s * 32 + (reg & 3) + 8 * (reg >> 2) + 4 * half;
#pragma unroll
        for (int dt = 0; dt < 4; ++dt)
          os[row * 128 + dt * 32 + l32] = oacc[s][dt][reg];
      }
  }
  __syncthreads();
  if (kg == 0 || kg == 2) {
    const float* os = slot + (qg * 2 + (kg >> 1)) * 8192;
#pragma unroll
    for (int s = 0; s < 2; ++s)
#pragma unroll
      for (int reg = 0; reg < 16; ++reg) {
        int row = s * 32 + (reg & 3) + 8 * (reg >> 2) + 4 * half;
#pragma unroll
        for (int dt = 0; dt < 4; ++dt)
          oacc[s][dt][reg] += os[row * 128 + dt * 32 + l32];
      }
  }
  __syncthreads();
  // round 2: kg2 -> slot[qg*2+0]
  if (kg == 2) {
    float* os = slot + (qg * 2) * 8192;
#pragma unroll
    for (int s = 0; s < 2; ++s)
#pragma unroll
      for (int reg = 0; reg < 16; ++reg) {
        int row = s * 32 + (reg & 3) + 8 * (reg >> 2) + 4 * half;
#pragma unroll
        for (int dt = 0; dt < 4; ++dt)
          os[row * 128 + dt * 32 + l32] = oacc[s][dt][reg];
      }
  }
  __syncthreads();
  if (kg == 0) {
    const float* os = slot + (qg * 2) * 8192;
    float tot0 = lt0, tot1 = lt1;
#pragma unroll
    for (int k = 0; k < 3; ++k) {
      const float* lw = larr + (k * 2 + qg) * 64;
      tot0 += lw[l32];
      tot1 += lw[32 + l32];
    }
    float* Ob = O + (size_t)b * S_LEN * D_DIM;
#pragma unroll
    for (int s = 0; s < 2; ++s) {
      float tot = s ? tot1 : tot0;
#pragma unroll
      for (int reg = 0; reg < 16; ++reg) {
        int crow = (reg & 3) + 8 * (reg >> 2) + 4 * half;
        int row  = s * 32 + crow;
        float linv = 1.f / __shfl(tot, crow);
#pragma unroll
        for (int dt = 0; dt < 4; ++dt)
          Ob[(size_t)(qbase + row) * D_DIM + dt * 32 + l32] =
              (oacc[s][dt][reg] + os[row * 128 + dt * 32 + l32]) * linv;
      }
    }
  }
}

extern "C" void kernel_launch(void* const* d_in, const int* in_sizes, int n_in,
                              void* d_out, int out_size, void* d_ws, size_t ws_size,
                              hipStream_t stream) {
  const float* Q = (const float*)d_in[0];
  const float* K = (const float*)d_in[1];
  const float* V = (const float*)d_in[2];
  float* O = (float*)d_out;
  unsigned short* Kb = (unsigned short*)d_ws;                       // 8.4 MB
  unsigned short* VT = Kb + (size_t)B_N * S_LEN * D_DIM;            // 8.4 MB
  prep_kernel<<<dim3(4096 + 1024), dim3(256), 0, stream>>>(K, V, Kb, VT);
  attn_kernel<<<dim3(256), dim3(512), 0, stream>>>(Q, Kb, VT, O);
}